// Round 5
// baseline (2089.196 us; speedup 1.0000x reference)
//
#include <hip/hip_runtime.h>

typedef __attribute__((ext_vector_type(8))) short bf16x8;
typedef __attribute__((ext_vector_type(4))) float f32x4;
typedef unsigned short u16;

__device__ __forceinline__ float bf2f(u16 u) {
  return __uint_as_float(((unsigned)u) << 16);
}
__device__ __forceinline__ u16 f2bf(float x) {
  unsigned u = __float_as_uint(x);
  u += 0x7fffu + ((u >> 16) & 1u);   // RNE
  return (u16)(u >> 16);
}
// flag-aware scalar input load (isbf: bf16, else fp32)
__device__ __forceinline__ float ldin(const void* p, size_t i, bool isbf) {
  return isbf ? bf2f(((const u16*)p)[i]) : ((const float*)p)[i];
}
// flag-aware 8-element load -> bf16 fragment chunk
__device__ __forceinline__ bf16x8 ld8cvt(const void* p, size_t off, bool isbf) {
  if (isbf) return *(const bf16x8*)((const u16*)p + off);
  const float* f = (const float*)p + off;
  float4 a = *(const float4*)f;
  float4 b = *(const float4*)(f + 4);
  bf16x8 r;
  r[0] = (short)f2bf(a.x); r[1] = (short)f2bf(a.y);
  r[2] = (short)f2bf(a.z); r[3] = (short)f2bf(a.w);
  r[4] = (short)f2bf(b.x); r[5] = (short)f2bf(b.y);
  r[6] = (short)f2bf(b.z); r[7] = (short)f2bf(b.w);
  return r;
}

// async global->LDS (vmcnt-counted; LDS dest = wave-uniform base + lane*size)
__device__ __forceinline__ void gld16(const void* g, void* l) {
  __builtin_amdgcn_global_load_lds(
      (const __attribute__((address_space(1))) unsigned*)g,
      (__attribute__((address_space(3))) unsigned*)l, 16, 0, 0);
}
__device__ __forceinline__ void gld4(const void* g, void* l) {
  __builtin_amdgcn_global_load_lds(
      (const __attribute__((address_space(1))) unsigned*)g,
      (__attribute__((address_space(3))) unsigned*)l, 4, 0, 0);
}

// ---------------------------------------------------------------------------
// Dtype detector: bf16 Gaussian data -> ~100% of shorts have exponent in
// [96,160) (or are exact zero); fp32 data read as bf16 pairs -> ~62%.
// ---------------------------------------------------------------------------
__global__ __launch_bounds__(256) void detect_dtype(const u16* __restrict__ X16,
                                                    int* __restrict__ flag) {
  __shared__ int cnt;
  if (threadIdx.x == 0) cnt = 0;
  __syncthreads();
  int c = 0;
#pragma unroll
  for (int i = 0; i < 8; ++i) {
    u16 v = X16[threadIdx.x * 8 + i];
    int e = (v >> 7) & 0xFF;
    bool sane = (e == 0) ? ((v & 0x7FFF) == 0) : (e >= 96 && e < 160);
    c += sane ? 1 : 0;
  }
  atomicAdd(&cnt, c);
  __syncthreads();
  if (threadIdx.x == 0) flag[0] = (cnt >= 1850) ? 1 : 0;  // 1 = bf16 inputs
}

// ---------------------------------------------------------------------------
// Generic MFMA GEMM: C[M,N] = A[M,K] @ B[N,K]^T, fp32 accumulate.
// A/B may be bf16 or fp32 (amode/bmode: 0=f32, 1=bf16, 2=per dflag).
// 128x128 tile, 256 threads = 4 waves (2x2), wave 64x64 via 4x4 of 16x16x32.
// ---------------------------------------------------------------------------
enum { EPI_F32 = 0, EPI_BF16 = 1, EPI_EG = 2, EPI_SIG = 3, EPI_OUT = 4 };
constexpr int LDT = 40;

__global__ __launch_bounds__(256) void gemm_any(
    const void* __restrict__ A, const void* __restrict__ B,
    float* __restrict__ Cf, u16* __restrict__ Cb,
    int M, int N, int K, int epi,
    const void* __restrict__ dtb, const void* __restrict__ alog,
    int amode, int bmode, const int* __restrict__ dflag) {
  const bool inbf = (dflag[0] != 0);
  const bool abf = (amode == 2) ? inbf : (amode == 1);
  const bool bbf = (bmode == 2) ? inbf : (bmode == 1);

  __shared__ __align__(16) short As[128 * LDT];
  __shared__ __align__(16) short Bs[128 * LDT];
  const int t = threadIdx.x;
  const int n0 = blockIdx.x * 128, m0 = blockIdx.y * 128;
  const int wave = t >> 6, lane = t & 63;
  const int wm = (wave >> 1) << 6, wn = (wave & 1) << 6;
  const int lm = lane & 15, lq = lane >> 4;

  f32x4 acc[4][4];
#pragma unroll
  for (int i = 0; i < 4; ++i)
#pragma unroll
    for (int j = 0; j < 4; ++j) {
      acc[i][j][0] = 0.f; acc[i][j][1] = 0.f;
      acc[i][j][2] = 0.f; acc[i][j][3] = 0.f;
    }

  const int ar = t >> 2;            // 0..63
  const int ac = (t & 3) << 3;      // 0,8,16,24

  for (int kb = 0; kb < K; kb += 32) {
#pragma unroll
    for (int p = 0; p < 2; ++p) {
      int r = ar + (p << 6);
      *(bf16x8*)&As[r * LDT + ac] =
          ld8cvt(A, (size_t)(m0 + r) * K + kb + ac, abf);
      *(bf16x8*)&Bs[r * LDT + ac] =
          ld8cvt(B, (size_t)(n0 + r) * K + kb + ac, bbf);
    }
    __syncthreads();

    bf16x8 af[4], bfr[4];
#pragma unroll
    for (int i = 0; i < 4; ++i)
      af[i] = *(const bf16x8*)&As[(wm + (i << 4) + lm) * LDT + (lq << 3)];
#pragma unroll
    for (int j = 0; j < 4; ++j)
      bfr[j] = *(const bf16x8*)&Bs[(wn + (j << 4) + lm) * LDT + (lq << 3)];
#pragma unroll
    for (int i = 0; i < 4; ++i)
#pragma unroll
      for (int j = 0; j < 4; ++j)
        acc[i][j] = __builtin_amdgcn_mfma_f32_16x16x32_bf16(
            af[i], bfr[j], acc[i][j], 0, 0, 0);
    __syncthreads();
  }

  // C/D layout (verified): col=lane&15, row=(lane>>4)*4+reg.
#pragma unroll
  for (int j = 0; j < 4; ++j) {
    const int col = n0 + wn + (j << 4) + lm;
    float dtv = 0.f, nA = 0.f;
    if (epi == EPI_EG) {
      dtv = ldin(dtb, col, inbf);
      nA = -expf(fminf(ldin(alog, col >> 7, inbf), 20.f));
    }
#pragma unroll
    for (int i = 0; i < 4; ++i) {
#pragma unroll
      for (int r = 0; r < 4; ++r) {
        const int row = m0 + wm + (i << 4) + (lq << 2) + r;
        const size_t off = (size_t)row * N + col;
        float v = acc[i][j][r];
        if (epi == EPI_F32) {
          Cf[off] = v;
        } else if (epi == EPI_BF16) {
          Cb[off] = f2bf(v);
        } else if (epi == EPI_EG) {
          float x = v + dtv;
          float sp = (x > 20.f) ? x : log1pf(expf(x));
          float arg = fmaxf(nA * sp, -87.f);   // clamp; fmaxf scrubs NaN
          Cf[off] = expf(arg);                 // exp(g) in (0,1]
        } else if (epi == EPI_SIG) {
          Cb[off] = f2bf(1.f / (1.f + expf(-v)));
        } else {                               // EPI_OUT: dtype per flag
          if (inbf) Cb[off] = f2bf(v);
          else      Cf[off] = v;
        }
      }
    }
  }
}

// ---------------------------------------------------------------------------
// Depthwise causal conv (K=4) + SiLU + optional L2-norm over dk=128.
// grid (N, H), block 128. mode: 0 none, 1 l2n, 2 l2n * dk^-0.5. out bf16.
// ---------------------------------------------------------------------------
__global__ __launch_bounds__(128) void conv_silu_norm(
    const float* __restrict__ proj, const void* __restrict__ cw,
    u16* __restrict__ out, int mode, const int* __restrict__ dflag) {
  const bool inbf = (dflag[0] != 0);
  const int n = blockIdx.x, h = blockIdx.y, d = threadIdx.x;
  const int col = (h << 7) + d;
  float w0, w1, w2, w3;
  if (inbf) {
    ushort4 wu = *(const ushort4*)((const u16*)cw + col * 4);
    w0 = bf2f(wu.x); w1 = bf2f(wu.y); w2 = bf2f(wu.z); w3 = bf2f(wu.w);
  } else {
    float4 wf = *(const float4*)((const float*)cw + col * 4);
    w0 = wf.x; w1 = wf.y; w2 = wf.z; w3 = wf.w;
  }
  const float* pc = proj + col;
  float acc = 0.f;
  if (n >= 3) acc = fmaf(pc[(size_t)(n - 3) * 4096], w0, acc);
  if (n >= 2) acc = fmaf(pc[(size_t)(n - 2) * 4096], w1, acc);
  if (n >= 1) acc = fmaf(pc[(size_t)(n - 1) * 4096], w2, acc);
  acc = fmaf(pc[(size_t)n * 4096], w3, acc);
  float y = acc / (1.f + expf(-acc));  // silu
  if (mode) {
    float s = y * y;
    s += __shfl_xor(s, 1);  s += __shfl_xor(s, 2);  s += __shfl_xor(s, 4);
    s += __shfl_xor(s, 8);  s += __shfl_xor(s, 16); s += __shfl_xor(s, 32);
    __shared__ float red[2];
    if ((d & 63) == 0) red[d >> 6] = s;
    __syncthreads();
    float sc = rsqrtf(red[0] + red[1] + 1e-6f);
    if (mode == 2) sc *= 0.08838834764831845f;  // dk^-0.5
    y *= sc;
  }
  out[(size_t)n * 4096 + col] = f2bf(y);
}

// ---------------------------------------------------------------------------
// beta = sigmoid(X @ Wb^T). block 64/row; lane t: head t&31, half t>>5.
// ---------------------------------------------------------------------------
__global__ __launch_bounds__(64) void beta_kernel(
    const void* __restrict__ X, const void* __restrict__ Wb,
    float* __restrict__ beta, const int* __restrict__ dflag) {
  const bool inbf = (dflag[0] != 0);
  const int n = blockIdx.x, t = threadIdx.x;
  const int hh = t & 31, half = t >> 5;
  const size_t xo = (size_t)n * 2048 + half * 1024;
  const size_t wo = (size_t)hh * 2048 + half * 1024;
  float acc = 0.f;
  if (inbf) {
    const u16* xr = (const u16*)X + xo;
    const u16* wr = (const u16*)Wb + wo;
    for (int j = 0; j < 1024; j += 4) {
      ushort4 xa = *(const ushort4*)(xr + j);
      ushort4 wa = *(const ushort4*)(wr + j);
      acc = fmaf(bf2f(xa.x), bf2f(wa.x), acc);
      acc = fmaf(bf2f(xa.y), bf2f(wa.y), acc);
      acc = fmaf(bf2f(xa.z), bf2f(wa.z), acc);
      acc = fmaf(bf2f(xa.w), bf2f(wa.w), acc);
    }
  } else {
    const float* xr = (const float*)X + xo;
    const float* wr = (const float*)Wb + wo;
    for (int j = 0; j < 1024; j += 4) {
      float4 xa = *(const float4*)(xr + j);
      float4 wa = *(const float4*)(wr + j);
      acc = fmaf(xa.x, wa.x, acc);
      acc = fmaf(xa.y, wa.y, acc);
      acc = fmaf(xa.z, wa.z, acc);
      acc = fmaf(xa.w, wa.w, acc);
    }
  }
  acc += __shfl_xor(acc, 32);
  if (half == 0) beta[(n << 5) + hh] = 1.f / (1.f + expf(-acc));
}

// ---------------------------------------------------------------------------
// DPP 16-lane row reduction: 4 dependent VALU adds, no LDS.
// ---------------------------------------------------------------------------
template <int CTRL>
__device__ __forceinline__ float dpp_add(float x) {
  int t = __builtin_amdgcn_update_dpp(0, __float_as_int(x), CTRL, 0xF, 0xF,
                                      true);
  return x + __int_as_float(t);
}
__device__ __forceinline__ float row16_sum(float x) {
  x = dpp_add<0xB1>(x);   // quad_perm [1,0,3,2] = xor1
  x = dpp_add<0x4E>(x);   // quad_perm [2,3,0,1] = xor2
  x = dpp_add<0x124>(x);  // row_ror:4
  x = dpp_add<0x128>(x);  // row_ror:8
  return x;
}
__device__ __forceinline__ void unp8(uint4 w, float* f) {
  f[0] = __uint_as_float(w.x << 16); f[1] = __uint_as_float(w.x & 0xffff0000u);
  f[2] = __uint_as_float(w.y << 16); f[3] = __uint_as_float(w.y & 0xffff0000u);
  f[4] = __uint_as_float(w.z << 16); f[5] = __uint_as_float(w.z & 0xffff0000u);
  f[6] = __uint_as_float(w.w << 16); f[7] = __uint_as_float(w.w & 0xffff0000u);
}

// ---------------------------------------------------------------------------
// Recurrent delta-rule scan, column-parallel, LDS chunk-staged.
// grid 256 = 32 heads x 8 v-blocks(16 cols); block 256 = 16 klanes x 16 v.
// Each lane owns 8 k-channels x 1 v; k-reduction = 16-lane DPP row sum.
//
// R4 post-mortem: staging works (537us, fetch 42MB, 0 conflicts) but
// VGPR=52 showed the compiler ALSO collapsed the LDS->reg pipeline under
// its default-occupancy register cap -> each step eats ~120cy+ LDS latency
// serially. Fix: __launch_bounds__(256, 1) (occupancy is grid-limited at
// 1 wave/SIMD, so the register budget is free) + explicit 1-step LDS->reg
// lookahead (load s+1's operands, then compute step s).
//
// XCD-local decode kept (R2/R3-proven: FETCH 297->43MB): h = bid&31 puts
// all 8 sharer-blocks of a head on one XCD (xcd = bid%8).
// ---------------------------------------------------------------------------
constexpr int CH = 16;  // steps per staged chunk

__device__ __forceinline__ void kda_step(float S[8], uint4 kw, uint4 qw,
                                         float4 ea, float4 eb, float vt,
                                         float bt, bool lead, float* cdst) {
  float kf[8], qf[8];
  unp8(kw, kf);
  unp8(qw, qf);
  S[0] *= ea.x; S[1] *= ea.y; S[2] *= ea.z; S[3] *= ea.w;
  S[4] *= eb.x; S[5] *= eb.y; S[6] *= eb.z; S[7] *= eb.w;
  float m0 = fmaf(S[1], kf[1], S[0] * kf[0]);
  float m1 = fmaf(S[3], kf[3], S[2] * kf[2]);
  float m2 = fmaf(S[5], kf[5], S[4] * kf[4]);
  float m3 = fmaf(S[7], kf[7], S[6] * kf[6]);
  float kv = row16_sum((m0 + m1) + (m2 + m3));
  float dl = (vt - kv) * bt;
  S[0] = fmaf(kf[0], dl, S[0]);
  S[1] = fmaf(kf[1], dl, S[1]);
  S[2] = fmaf(kf[2], dl, S[2]);
  S[3] = fmaf(kf[3], dl, S[3]);
  S[4] = fmaf(kf[4], dl, S[4]);
  S[5] = fmaf(kf[5], dl, S[5]);
  S[6] = fmaf(kf[6], dl, S[6]);
  S[7] = fmaf(kf[7], dl, S[7]);
  float o0 = fmaf(S[1], qf[1], S[0] * qf[0]);
  float o1 = fmaf(S[3], qf[3], S[2] * qf[2]);
  float o2 = fmaf(S[5], qf[5], S[4] * qf[4]);
  float o3 = fmaf(S[7], qf[7], S[6] * qf[6]);
  float o = row16_sum((o0 + o1) + (o2 + o3));
  if (lead) *cdst = o;
}

__global__ __launch_bounds__(256, 1) void scan_kernel(
    const u16* __restrict__ q, const u16* __restrict__ k,
    const u16* __restrict__ v, const float* __restrict__ eg,
    const float* __restrict__ beta, float* __restrict__ core) {
  const int h = blockIdx.x & 31, vb = blockIdx.x >> 5;  // XCD-local decode
  const int t = threadIdx.x;
  const int kl = t & 15;           // k-lane: owns channels [kl*8, kl*8+8)
  const int vloc = t >> 4;         // 0..15
  const bool lead = (kl == 0);
  float S[8] = {0.f, 0.f, 0.f, 0.f, 0.f, 0.f, 0.f, 0.f};

  // LDS double buffers (33.1 KB total)
  __shared__ __align__(16) u16   kS[2][CH * 128];   // 4 KB/buf
  __shared__ __align__(16) u16   qS[2][CH * 128];   // 4 KB/buf
  __shared__ __align__(16) float eS[2][CH * 128];   // 8 KB/buf (ea|eb blocks)
  __shared__ __align__(16) u16   vS[2][CH * 16];    // 512 B/buf
  __shared__ __align__(16) float bS[2][CH];         // 64 B/buf

  const u16*   khead = k + (h << 7);
  const u16*   qhead = q + (h << 7);
  const float* ehead = eg + (h << 7);
  const u16*   vhead = v + (h << 7) + (vb << 4);
  const float* bhead = beta + h;
  float*       cp    = core + (h << 7) + (vb << 4) + vloc;

  const int wb  = t >> 6;                 // wave id (LDS base must be
  const int r16 = t >> 4, j16 = t & 15;   //   wave-uniform; dest=base+lane*sz)
  const int r32 = t >> 5, j32 = t & 31;
  // eg source permutation: LDS piece j holds ea of kl=j (j<16) else eb of
  // kl=j-16 -> src float offset:
  const int esrc = ((j32 & 15) << 3) + ((j32 >> 4) << 2);

#define STAGE(buf, n0)                                                        \
  {                                                                           \
    gld16(khead + (size_t)((n0) + r16) * 4096 + (j16 << 3),                   \
          &kS[buf][wb << 9]);                                                 \
    gld16(qhead + (size_t)((n0) + r16) * 4096 + (j16 << 3),                   \
          &qS[buf][wb << 9]);                                                 \
    gld16(ehead + (size_t)((n0) + r32) * 4096 + esrc,                         \
          &eS[buf][wb << 8]);                                                 \
    gld16(ehead + (size_t)((n0) + 8 + r32) * 4096 + esrc,                     \
          &eS[buf][1024 + (wb << 8)]);                                        \
    if (t < 32)                                                               \
      gld16(vhead + (size_t)((n0) + (t >> 1)) * 4096 + ((t & 1) << 3),        \
            &vS[buf][0]);                                                     \
    if (t < 16) gld4(bhead + (size_t)((n0) + t) * 32, &bS[buf][0]);           \
  }

  // per-step LDS operand fetch into registers
#define LDOP(buf, s, KW, QW, EA, EB, VT, BT)                                  \
  {                                                                           \
    KW = *(const uint4*)&kS[buf][((s) << 7) + (kl << 3)];                     \
    QW = *(const uint4*)&qS[buf][((s) << 7) + (kl << 3)];                     \
    EA = *(const float4*)&eS[buf][((s) << 7) + (kl << 2)];                    \
    EB = *(const float4*)&eS[buf][((s) << 7) + 64 + (kl << 2)];               \
    VT = bf2f(vS[buf][((s) << 4) + vloc]);                                    \
    BT = bS[buf][s];                                                          \
  }

  STAGE(0, 0)
  __syncthreads();  // drains vmcnt: chunk 0 resident

  uint4 kw, qw, kwn, qwn;
  float4 ea, eb, ean, ebn;
  float vt, bt, vtn, btn;

  for (int c = 0; c < 2048 / CH; ++c) {
    const int buf = c & 1;
    if (c + 1 < 2048 / CH) STAGE(buf ^ 1, (c + 1) * CH)
    LDOP(buf, 0, kw, qw, ea, eb, vt, bt)
#pragma unroll
    for (int s = 0; s < CH; ++s) {
      const int sn = (s + 1 < CH) ? s + 1 : s;  // clamped lookahead
      LDOP(buf, sn, kwn, qwn, ean, ebn, vtn, btn)
      kda_step(S, kw, qw, ea, eb, vt, bt, lead,
               cp + ((size_t)(c * CH + s) << 12));
      kw = kwn; qw = qwn; ea = ean; eb = ebn; vt = vtn; bt = btn;
    }
    __syncthreads();  // drains vmcnt: next chunk resident, cur reads done
  }
#undef STAGE
#undef LDOP
}

// ---------------------------------------------------------------------------
// Gated RMSNorm: rms(core) * onorm_w * sigmoid_gate, output bf16.
// ---------------------------------------------------------------------------
__global__ __launch_bounds__(128) void rms_gate(
    const float* __restrict__ core, const u16* __restrict__ sg,
    const void* __restrict__ onw, u16* __restrict__ rb,
    const int* __restrict__ dflag) {
  const bool inbf = (dflag[0] != 0);
  const int n = blockIdx.x, h = blockIdx.y, d = threadIdx.x;
  const int col = (h << 7) + d;
  const size_t off = ((size_t)n << 12) + col;
  float x = core[off];
  float s = x * x;
  s += __shfl_xor(s, 1);  s += __shfl_xor(s, 2);  s += __shfl_xor(s, 4);
  s += __shfl_xor(s, 8);  s += __shfl_xor(s, 16); s += __shfl_xor(s, 32);
  __shared__ float red[2];
  if ((d & 63) == 0) red[d >> 6] = s;
  __syncthreads();
  float tot = red[0] + red[1];
  float r = x * rsqrtf(tot * 0.0078125f + 1e-5f);  // mean over 128
  rb[off] = f2bf(r * ldin(onw, d, inbf) * bf2f(sg[off]));
}

// ---------------------------------------------------------------------------
extern "C" void kernel_launch(void* const* d_in, const int* in_sizes, int n_in,
                              void* d_out, int out_size, void* d_ws, size_t ws_size,
                              hipStream_t stream) {
  const void* X    = d_in[0];
  const void* Wq   = d_in[1];
  const void* Wk   = d_in[2];
  const void* Wv   = d_in[3];
  const void* cq   = d_in[4];
  const void* ck   = d_in[5];
  const void* cv   = d_in[6];
  const void* Wfa  = d_in[7];
  const void* Wfb  = d_in[8];
  const void* dtb  = d_in[9];
  const void* Wb   = d_in[10];
  const void* Alog = d_in[11];
  const void* Wga  = d_in[12];
  const void* Wgb  = d_in[13];
  const void* onw  = d_in[14];
  const void* Wo   = d_in[15];
  char* W = (char*)d_ws;

  const size_t MB = 1024 * 1024;
  const size_t NEED = 114 * MB;
  if (ws_size < NEED) {
    hipMemsetAsync(d_out, 0, (size_t)out_size * 2, stream);
    return;
  }

  float* proj  = (float*)(W);                 // 32M fp32; core aliases
  u16*   qb    = (u16*)(W + 32 * MB);         // 16M bf16; rmsb aliases
  u16*   kb    = (u16*)(W + 48 * MB);         // 16M bf16; sgb aliases
  u16*   vb    = (u16*)(W + 64 * MB);         // 16M bf16
  float* eg    = (float*)(W + 80 * MB);       // 32M fp32
  u16*   flowb = (u16*)(W + 112 * MB);        // 512K
  u16*   glowb = (u16*)(W + 112 * MB + 512 * 1024);
  float* betab = (float*)(W + 113 * MB);      // 256K
  int*   dflag = (int*)(W + 113 * MB + 256 * 1024);
  float* core  = proj;
  u16*   sgb   = kb;
  u16*   rmsb  = qb;

  const dim3 gBig(32, 16);    // C [2048,4096]
  const dim3 gLow(1, 16);     // C [2048,128]
  const dim3 gOut(16, 16);    // C [2048,2048]
  const dim3 gNH(2048, 32);

  detect_dtype<<<1, 256, 0, stream>>>((const u16*)X, dflag);

  gemm_any<<<gBig, 256, 0, stream>>>(X, Wq, proj, nullptr, 2048, 4096, 2048,
                                     EPI_F32, nullptr, nullptr, 2, 2, dflag);
  conv_silu_norm<<<gNH, 128, 0, stream>>>(proj, cq, qb, 2, dflag);
  gemm_any<<<gBig, 256, 0, stream>>>(X, Wk, proj, nullptr, 2048, 4096, 2048,
                                     EPI_F32, nullptr, nullptr, 2, 2, dflag);
  conv_silu_norm<<<gNH, 128, 0, stream>>>(proj, ck, kb, 1, dflag);
  gemm_any<<<gBig, 256, 0, stream>>>(X, Wv, proj, nullptr, 2048, 4096, 2048,
                                     EPI_F32, nullptr, nullptr, 2, 2, dflag);
  conv_silu_norm<<<gNH, 128, 0, stream>>>(proj, cv, vb, 0, dflag);

  gemm_any<<<gLow, 256, 0, stream>>>(X, Wfa, nullptr, flowb, 2048, 128, 2048,
                                     EPI_BF16, nullptr, nullptr, 2, 2, dflag);
  gemm_any<<<gLow, 256, 0, stream>>>(X, Wga, nullptr, glowb, 2048, 128, 2048,
                                     EPI_BF16, nullptr, nullptr, 2, 2, dflag);
  beta_kernel<<<2048, 64, 0, stream>>>(X, Wb, betab, dflag);

  gemm_any<<<gBig, 256, 0, stream>>>(flowb, Wfb, eg, nullptr, 2048, 4096, 128,
                                     EPI_EG, dtb, Alog, 1, 2, dflag);

  scan_kernel<<<256, 256, 0, stream>>>(qb, kb, vb, eg, betab, core);

  gemm_any<<<gBig, 256, 0, stream>>>(glowb, Wgb, nullptr, sgb, 2048, 4096, 128,
                                     EPI_SIG, nullptr, nullptr, 1, 2, dflag);
  rms_gate<<<gNH, 128, 0, stream>>>(core, sgb, onw, rmsb, dflag);

  gemm_any<<<gOut, 256, 0, stream>>>(rmsb, Wo, (float*)d_out, (u16*)d_out,
                                     2048, 2048, 4096, EPI_OUT,
                                     nullptr, nullptr, 1, 2, dflag);
}

// Round 7
// 1329.474 us; speedup vs baseline: 1.5714x; 1.5714x over previous
//
#include <hip/hip_runtime.h>

typedef __attribute__((ext_vector_type(8))) short bf16x8;
typedef __attribute__((ext_vector_type(4))) float f32x4;
typedef unsigned short u16;

__device__ __forceinline__ float bf2f(u16 u) {
  return __uint_as_float(((unsigned)u) << 16);
}
__device__ __forceinline__ u16 f2bf(float x) {
  unsigned u = __float_as_uint(x);
  u += 0x7fffu + ((u >> 16) & 1u);   // RNE
  return (u16)(u >> 16);
}
// flag-aware scalar input load (isbf: bf16, else fp32)
__device__ __forceinline__ float ldin(const void* p, size_t i, bool isbf) {
  return isbf ? bf2f(((const u16*)p)[i]) : ((const float*)p)[i];
}

// async global->LDS (vmcnt-counted; LDS dest = wave-uniform base + lane*size)
__device__ __forceinline__ void gld16(const void* g, void* l) {
  __builtin_amdgcn_global_load_lds(
      (const __attribute__((address_space(1))) unsigned*)g,
      (__attribute__((address_space(3))) unsigned*)l, 16, 0, 0);
}
__device__ __forceinline__ void gld4(const void* g, void* l) {
  __builtin_amdgcn_global_load_lds(
      (const __attribute__((address_space(1))) unsigned*)g,
      (__attribute__((address_space(3))) unsigned*)l, 4, 0, 0);
}

// ---------------------------------------------------------------------------
// Dtype detector: bf16 Gaussian data -> ~100% of shorts have exponent in
// [96,160) (or are exact zero); fp32 data read as bf16 pairs -> ~62%.
// ---------------------------------------------------------------------------
__global__ __launch_bounds__(256) void detect_dtype(const u16* __restrict__ X16,
                                                    int* __restrict__ flag) {
  __shared__ int cnt;
  if (threadIdx.x == 0) cnt = 0;
  __syncthreads();
  int c = 0;
#pragma unroll
  for (int i = 0; i < 8; ++i) {
    u16 v = X16[threadIdx.x * 8 + i];
    int e = (v >> 7) & 0xFF;
    bool sane = (e == 0) ? ((v & 0x7FFF) == 0) : (e >= 96 && e < 160);
    c += sane ? 1 : 0;
  }
  atomicAdd(&cnt, c);
  __syncthreads();
  if (threadIdx.x == 0) flag[0] = (cnt >= 1850) ? 1 : 0;  // 1 = bf16 inputs
}

// ---------------------------------------------------------------------------
// fp32->bf16 (RNE, identical to the old in-GEMM f2bf) or bf16 copy, by dflag.
// n8 = element count / 8. Grid-stride.
// ---------------------------------------------------------------------------
__global__ __launch_bounds__(256) void cvt_bf16(const void* __restrict__ src,
                                                u16* __restrict__ dst, int n8,
                                                const int* __restrict__ dflag) {
  const bool inbf = (dflag[0] != 0);
  const int stride = gridDim.x * 256;
  for (int i = blockIdx.x * 256 + threadIdx.x; i < n8; i += stride) {
    uint4 o;
    if (inbf) {
      o = *(const uint4*)((const u16*)src + (size_t)i * 8);
    } else {
      const float* f = (const float*)src + (size_t)i * 8;
      float4 a = *(const float4*)f;
      float4 b = *(const float4*)(f + 4);
      o.x = (unsigned)f2bf(a.x) | ((unsigned)f2bf(a.y) << 16);
      o.y = (unsigned)f2bf(a.z) | ((unsigned)f2bf(a.w) << 16);
      o.z = (unsigned)f2bf(b.x) | ((unsigned)f2bf(b.y) << 16);
      o.w = (unsigned)f2bf(b.z) | ((unsigned)f2bf(b.w) << 16);
    }
    *(uint4*)(dst + (size_t)i * 8) = o;
  }
}

// ---------------------------------------------------------------------------
// bf16 MFMA GEMM: C[M,N] = A[M,K] @ B[N,K]^T, fp32 accumulate.
// A,B bf16 in memory (pre-converted). 128x128 tile, 256 thr = 4 waves (2x2),
// wave 64x64 via 4x4 of 16x16x32. Staging via global_load_lds width=16 into
// LINEAR LDS [128][32] (guide ladder step 3: removes the VALU staging tax;
// old gemm_any's per-element f2bf at stage time made it ~150 TF on fp32
// inputs). Single-buffered 2-barrier K-loop (syncthreads drains vmcnt).
// ---------------------------------------------------------------------------
enum { EPI_F32 = 0, EPI_BF16 = 1, EPI_EG = 2, EPI_SIG = 3, EPI_OUT = 4 };

__global__ __launch_bounds__(256, 2) void gemm_bf16(
    const u16* __restrict__ A, const u16* __restrict__ B,
    float* __restrict__ Cf, u16* __restrict__ Cb,
    int M, int N, int K, int epi,
    const void* __restrict__ dtb, const void* __restrict__ alog,
    const int* __restrict__ dflag) {
  const bool inbf = (dflag[0] != 0);
  __shared__ __align__(16) u16 As[128 * 32];
  __shared__ __align__(16) u16 Bs[128 * 32];
  const int t = threadIdx.x;
  const int n0 = blockIdx.x * 128, m0 = blockIdx.y * 128;
  const int wv = t >> 6, lane = t & 63;
  const int wm = (wv >> 1) << 6, wn = (wv & 1) << 6;
  const int lm = lane & 15, lq = lane >> 4;

  // staging: wave wv covers rows [wv*32, wv*32+32) in two gld16 issues;
  // lane l -> row +l/4, col (l&3)*8  (lds dest = uniform base + lane*16B)
  const int srow = (wv << 5) + (lane >> 2);
  const int scol = (lane & 3) << 3;
  const u16* ga0 = A + (size_t)(m0 + srow) * K + scol;
  const u16* ga1 = ga0 + (size_t)16 * K;
  const u16* gb0 = B + (size_t)(n0 + srow) * K + scol;
  const u16* gb1 = gb0 + (size_t)16 * K;
  u16* la0 = &As[(wv << 5) << 5];
  u16* la1 = &As[((wv << 5) + 16) << 5];
  u16* lb0 = &Bs[(wv << 5) << 5];
  u16* lb1 = &Bs[((wv << 5) + 16) << 5];

  f32x4 acc[4][4];
#pragma unroll
  for (int i = 0; i < 4; ++i)
#pragma unroll
    for (int j = 0; j < 4; ++j) {
      acc[i][j][0] = 0.f; acc[i][j][1] = 0.f;
      acc[i][j][2] = 0.f; acc[i][j][3] = 0.f;
    }

  for (int kb = 0; kb < K; kb += 32) {
    gld16(ga0 + kb, la0);
    gld16(ga1 + kb, la1);
    gld16(gb0 + kb, lb0);
    gld16(gb1 + kb, lb1);
    __syncthreads();  // drains vmcnt: tile resident

    bf16x8 af[4], bfr[4];
#pragma unroll
    for (int i = 0; i < 4; ++i)
      af[i] = *(const bf16x8*)&As[((wm + (i << 4) + lm) << 5) + (lq << 3)];
#pragma unroll
    for (int j = 0; j < 4; ++j)
      bfr[j] = *(const bf16x8*)&Bs[((wn + (j << 4) + lm) << 5) + (lq << 3)];
#pragma unroll
    for (int i = 0; i < 4; ++i)
#pragma unroll
      for (int j = 0; j < 4; ++j)
        acc[i][j] = __builtin_amdgcn_mfma_f32_16x16x32_bf16(
            af[i], bfr[j], acc[i][j], 0, 0, 0);
    __syncthreads();  // all reads done before next-tile overwrite
  }

  // C/D layout (verified): col=lane&15, row=(lane>>4)*4+reg.
#pragma unroll
  for (int j = 0; j < 4; ++j) {
    const int col = n0 + wn + (j << 4) + lm;
    float dtv = 0.f, nA = 0.f;
    if (epi == EPI_EG) {
      dtv = ldin(dtb, col, inbf);
      nA = -expf(fminf(ldin(alog, col >> 7, inbf), 20.f));
    }
#pragma unroll
    for (int i = 0; i < 4; ++i) {
#pragma unroll
      for (int r = 0; r < 4; ++r) {
        const int row = m0 + wm + (i << 4) + (lq << 2) + r;
        const size_t off = (size_t)row * N + col;
        float v = acc[i][j][r];
        if (epi == EPI_F32) {
          Cf[off] = v;
        } else if (epi == EPI_BF16) {
          Cb[off] = f2bf(v);
        } else if (epi == EPI_EG) {
          float x = v + dtv;
          float sp = (x > 20.f) ? x : log1pf(expf(x));
          float arg = fmaxf(nA * sp, -87.f);   // clamp; fmaxf scrubs NaN
          Cf[off] = expf(arg);                 // exp(g) in (0,1]
        } else if (epi == EPI_SIG) {
          Cb[off] = f2bf(1.f / (1.f + expf(-v)));
        } else {                               // EPI_OUT: dtype per flag
          if (inbf) Cb[off] = f2bf(v);
          else      Cf[off] = v;
        }
      }
    }
  }
}

// ---------------------------------------------------------------------------
// Depthwise causal conv (K=4) + SiLU + optional L2-norm over dk=128.
// grid (N, H), block 128. mode: 0 none, 1 l2n, 2 l2n * dk^-0.5. out bf16.
// ---------------------------------------------------------------------------
__global__ __launch_bounds__(128) void conv_silu_norm(
    const float* __restrict__ proj, const void* __restrict__ cw,
    u16* __restrict__ out, int mode, const int* __restrict__ dflag) {
  const bool inbf = (dflag[0] != 0);
  const int n = blockIdx.x, h = blockIdx.y, d = threadIdx.x;
  const int col = (h << 7) + d;
  float w0, w1, w2, w3;
  if (inbf) {
    ushort4 wu = *(const ushort4*)((const u16*)cw + col * 4);
    w0 = bf2f(wu.x); w1 = bf2f(wu.y); w2 = bf2f(wu.z); w3 = bf2f(wu.w);
  } else {
    float4 wf = *(const float4*)((const float*)cw + col * 4);
    w0 = wf.x; w1 = wf.y; w2 = wf.z; w3 = wf.w;
  }
  const float* pc = proj + col;
  float acc = 0.f;
  if (n >= 3) acc = fmaf(pc[(size_t)(n - 3) * 4096], w0, acc);
  if (n >= 2) acc = fmaf(pc[(size_t)(n - 2) * 4096], w1, acc);
  if (n >= 1) acc = fmaf(pc[(size_t)(n - 1) * 4096], w2, acc);
  acc = fmaf(pc[(size_t)n * 4096], w3, acc);
  float y = acc / (1.f + expf(-acc));  // silu
  if (mode) {
    float s = y * y;
    s += __shfl_xor(s, 1);  s += __shfl_xor(s, 2);  s += __shfl_xor(s, 4);
    s += __shfl_xor(s, 8);  s += __shfl_xor(s, 16); s += __shfl_xor(s, 32);
    __shared__ float red[2];
    if ((d & 63) == 0) red[d >> 6] = s;
    __syncthreads();
    float sc = rsqrtf(red[0] + red[1] + 1e-6f);
    if (mode == 2) sc *= 0.08838834764831845f;  // dk^-0.5
    y *= sc;
  }
  out[(size_t)n * 4096 + col] = f2bf(y);
}

// ---------------------------------------------------------------------------
// beta = sigmoid(X @ Wb^T). block 64/row; lane t: head t&31, half t>>5.
// Reads RAW inputs (fp32 path stays fp32) -> numerics identical to before.
// ---------------------------------------------------------------------------
__global__ __launch_bounds__(64) void beta_kernel(
    const void* __restrict__ X, const void* __restrict__ Wb,
    float* __restrict__ beta, const int* __restrict__ dflag) {
  const bool inbf = (dflag[0] != 0);
  const int n = blockIdx.x, t = threadIdx.x;
  const int hh = t & 31, half = t >> 5;
  const size_t xo = (size_t)n * 2048 + half * 1024;
  const size_t wo = (size_t)hh * 2048 + half * 1024;
  float acc = 0.f;
  if (inbf) {
    const u16* xr = (const u16*)X + xo;
    const u16* wr = (const u16*)Wb + wo;
    for (int j = 0; j < 1024; j += 4) {
      ushort4 xa = *(const ushort4*)(xr + j);
      ushort4 wa = *(const ushort4*)(wr + j);
      acc = fmaf(bf2f(xa.x), bf2f(wa.x), acc);
      acc = fmaf(bf2f(xa.y), bf2f(wa.y), acc);
      acc = fmaf(bf2f(xa.z), bf2f(wa.z), acc);
      acc = fmaf(bf2f(xa.w), bf2f(wa.w), acc);
    }
  } else {
    const float* xr = (const float*)X + xo;
    const float* wr = (const float*)Wb + wo;
    for (int j = 0; j < 1024; j += 4) {
      float4 xa = *(const float4*)(xr + j);
      float4 wa = *(const float4*)(wr + j);
      acc = fmaf(xa.x, wa.x, acc);
      acc = fmaf(xa.y, wa.y, acc);
      acc = fmaf(xa.z, wa.z, acc);
      acc = fmaf(xa.w, wa.w, acc);
    }
  }
  acc += __shfl_xor(acc, 32);
  if (half == 0) beta[(n << 5) + hh] = 1.f / (1.f + expf(-acc));
}

// ---------------------------------------------------------------------------
// DPP 16-lane row reduction: 4 dependent VALU adds, no LDS.
// ---------------------------------------------------------------------------
template <int CTRL>
__device__ __forceinline__ float dpp_add(float x) {
  int t = __builtin_amdgcn_update_dpp(0, __float_as_int(x), CTRL, 0xF, 0xF,
                                      true);
  return x + __int_as_float(t);
}
__device__ __forceinline__ float row16_sum(float x) {
  x = dpp_add<0xB1>(x);   // quad_perm [1,0,3,2] = xor1
  x = dpp_add<0x4E>(x);   // quad_perm [2,3,0,1] = xor2
  x = dpp_add<0x124>(x);  // row_ror:4
  x = dpp_add<0x128>(x);  // row_ror:8
  return x;
}
__device__ __forceinline__ void unp8(uint4 w, float* f) {
  f[0] = __uint_as_float(w.x << 16); f[1] = __uint_as_float(w.x & 0xffff0000u);
  f[2] = __uint_as_float(w.y << 16); f[3] = __uint_as_float(w.y & 0xffff0000u);
  f[4] = __uint_as_float(w.z << 16); f[5] = __uint_as_float(w.z & 0xffff0000u);
  f[6] = __uint_as_float(w.w << 16); f[7] = __uint_as_float(w.w & 0xffff0000u);
}

// ---------------------------------------------------------------------------
// Recurrent delta-rule scan, column-parallel, LDS chunk-staged (R4/R5 form,
// 500us; frozen this round). grid 256 = 32 heads x 8 v-blocks; block 256 =
// 16 klanes x 16 v. XCD-local decode h=bid&31 (FETCH 297->43MB proven).
// ---------------------------------------------------------------------------
constexpr int CH = 16;  // steps per staged chunk

__device__ __forceinline__ void kda_step(float S[8], uint4 kw, uint4 qw,
                                         float4 ea, float4 eb, float vt,
                                         float bt, bool lead, float* cdst) {
  float kf[8], qf[8];
  unp8(kw, kf);
  unp8(qw, qf);
  S[0] *= ea.x; S[1] *= ea.y; S[2] *= ea.z; S[3] *= ea.w;
  S[4] *= eb.x; S[5] *= eb.y; S[6] *= eb.z; S[7] *= eb.w;
  float m0 = fmaf(S[1], kf[1], S[0] * kf[0]);
  float m1 = fmaf(S[3], kf[3], S[2] * kf[2]);
  float m2 = fmaf(S[5], kf[5], S[4] * kf[4]);
  float m3 = fmaf(S[7], kf[7], S[6] * kf[6]);
  float kv = row16_sum((m0 + m1) + (m2 + m3));
  float dl = (vt - kv) * bt;
  S[0] = fmaf(kf[0], dl, S[0]);
  S[1] = fmaf(kf[1], dl, S[1]);
  S[2] = fmaf(kf[2], dl, S[2]);
  S[3] = fmaf(kf[3], dl, S[3]);
  S[4] = fmaf(kf[4], dl, S[4]);
  S[5] = fmaf(kf[5], dl, S[5]);
  S[6] = fmaf(kf[6], dl, S[6]);
  S[7] = fmaf(kf[7], dl, S[7]);
  float o0 = fmaf(S[1], qf[1], S[0] * qf[0]);
  float o1 = fmaf(S[3], qf[3], S[2] * qf[2]);
  float o2 = fmaf(S[5], qf[5], S[4] * qf[4]);
  float o3 = fmaf(S[7], qf[7], S[6] * qf[6]);
  float o = row16_sum((o0 + o1) + (o2 + o3));
  if (lead) *cdst = o;
}

__global__ __launch_bounds__(256, 1) void scan_kernel(
    const u16* __restrict__ q, const u16* __restrict__ k,
    const u16* __restrict__ v, const float* __restrict__ eg,
    const float* __restrict__ beta, float* __restrict__ core) {
  const int h = blockIdx.x & 31, vb = blockIdx.x >> 5;  // XCD-local decode
  const int t = threadIdx.x;
  const int kl = t & 15;           // k-lane: owns channels [kl*8, kl*8+8)
  const int vloc = t >> 4;         // 0..15
  const bool lead = (kl == 0);
  float S[8] = {0.f, 0.f, 0.f, 0.f, 0.f, 0.f, 0.f, 0.f};

  // LDS double buffers (33.1 KB total)
  __shared__ __align__(16) u16   kS[2][CH * 128];   // 4 KB/buf
  __shared__ __align__(16) u16   qS[2][CH * 128];   // 4 KB/buf
  __shared__ __align__(16) float eS[2][CH * 128];   // 8 KB/buf (ea|eb blocks)
  __shared__ __align__(16) u16   vS[2][CH * 16];    // 512 B/buf
  __shared__ __align__(16) float bS[2][CH];         // 64 B/buf

  const u16*   khead = k + (h << 7);
  const u16*   qhead = q + (h << 7);
  const float* ehead = eg + (h << 7);
  const u16*   vhead = v + (h << 7) + (vb << 4);
  const float* bhead = beta + h;
  float*       cp    = core + (h << 7) + (vb << 4) + vloc;

  const int wb  = t >> 6;                 // wave id (LDS base must be
  const int r16 = t >> 4, j16 = t & 15;   //   wave-uniform; dest=base+lane*sz)
  const int r32 = t >> 5, j32 = t & 31;
  // eg source permutation: LDS piece j holds ea of kl=j (j<16) else eb of
  // kl=j-16 -> src float offset:
  const int esrc = ((j32 & 15) << 3) + ((j32 >> 4) << 2);

#define STAGE(buf, n0)                                                        \
  {                                                                           \
    gld16(khead + (size_t)((n0) + r16) * 4096 + (j16 << 3),                   \
          &kS[buf][wb << 9]);                                                 \
    gld16(qhead + (size_t)((n0) + r16) * 4096 + (j16 << 3),                   \
          &qS[buf][wb << 9]);                                                 \
    gld16(ehead + (size_t)((n0) + r32) * 4096 + esrc,                         \
          &eS[buf][wb << 8]);                                                 \
    gld16(ehead + (size_t)((n0) + 8 + r32) * 4096 + esrc,                     \
          &eS[buf][1024 + (wb << 8)]);                                        \
    if (t < 32)                                                               \
      gld16(vhead + (size_t)((n0) + (t >> 1)) * 4096 + ((t & 1) << 3),        \
            &vS[buf][0]);                                                     \
    if (t < 16) gld4(bhead + (size_t)((n0) + t) * 32, &bS[buf][0]);           \
  }

  // per-step LDS operand fetch into registers
#define LDOP(buf, s, KW, QW, EA, EB, VT, BT)                                  \
  {                                                                           \
    KW = *(const uint4*)&kS[buf][((s) << 7) + (kl << 3)];                     \
    QW = *(const uint4*)&qS[buf][((s) << 7) + (kl << 3)];                     \
    EA = *(const float4*)&eS[buf][((s) << 7) + (kl << 2)];                    \
    EB = *(const float4*)&eS[buf][((s) << 7) + 64 + (kl << 2)];               \
    VT = bf2f(vS[buf][((s) << 4) + vloc]);                                    \
    BT = bS[buf][s];                                                          \
  }

  STAGE(0, 0)
  __syncthreads();  // drains vmcnt: chunk 0 resident

  uint4 kw, qw, kwn, qwn;
  float4 ea, eb, ean, ebn;
  float vt, bt, vtn, btn;

  for (int c = 0; c < 2048 / CH; ++c) {
    const int buf = c & 1;
    if (c + 1 < 2048 / CH) STAGE(buf ^ 1, (c + 1) * CH)
    LDOP(buf, 0, kw, qw, ea, eb, vt, bt)
#pragma unroll
    for (int s = 0; s < CH; ++s) {
      const int sn = (s + 1 < CH) ? s + 1 : s;  // clamped lookahead
      LDOP(buf, sn, kwn, qwn, ean, ebn, vtn, btn)
      kda_step(S, kw, qw, ea, eb, vt, bt, lead,
               cp + ((size_t)(c * CH + s) << 12));
      kw = kwn; qw = qwn; ea = ean; eb = ebn; vt = vtn; bt = btn;
    }
    __syncthreads();  // drains vmcnt: next chunk resident, cur reads done
  }
#undef STAGE
#undef LDOP
}

// ---------------------------------------------------------------------------
// Gated RMSNorm: rms(core) * onorm_w * sigmoid_gate, output bf16.
// ---------------------------------------------------------------------------
__global__ __launch_bounds__(128) void rms_gate(
    const float* __restrict__ core, const u16* __restrict__ sg,
    const void* __restrict__ onw, u16* __restrict__ rb,
    const int* __restrict__ dflag) {
  const bool inbf = (dflag[0] != 0);
  const int n = blockIdx.x, h = blockIdx.y, d = threadIdx.x;
  const int col = (h << 7) + d;
  const size_t off = ((size_t)n << 12) + col;
  float x = core[off];
  float s = x * x;
  s += __shfl_xor(s, 1);  s += __shfl_xor(s, 2);  s += __shfl_xor(s, 4);
  s += __shfl_xor(s, 8);  s += __shfl_xor(s, 16); s += __shfl_xor(s, 32);
  __shared__ float red[2];
  if ((d & 63) == 0) red[d >> 6] = s;
  __syncthreads();
  float tot = red[0] + red[1];
  float r = x * rsqrtf(tot * 0.0078125f + 1e-5f);  // mean over 128
  rb[off] = f2bf(r * ldin(onw, d, inbf) * bf2f(sg[off]));
}

// ---------------------------------------------------------------------------
// Workspace timeline (NEED stays 114MB; bf16 weight copies aliased into
// dead windows):
//   proj/core @0 (32M)    : GEMM fp32 out -> convs; small bf16 weights
//                           (Wfa16@0, Wga16@1M, Wfb16@2M) after conv v,
//                           all consumed before scan overwrites as core
//   qb @32M, kb @48M, vb @64M (16M each); sgb=kb, rmsb=qb after scan;
//                           Wgb16@64M (post-scan), then Wo16@64M (16M exact)
//   eg @80M (32M)         : x16@80M (8M) + w16@88M (16M) live until EG-gemm
//                           writes eg (x16/w16 dead by then)
//   flowb @112M, glowb @112.5M, betab @113M, dflag @113.25M
// ---------------------------------------------------------------------------
extern "C" void kernel_launch(void* const* d_in, const int* in_sizes, int n_in,
                              void* d_out, int out_size, void* d_ws, size_t ws_size,
                              hipStream_t stream) {
  const void* X    = d_in[0];
  const void* Wq   = d_in[1];
  const void* Wk   = d_in[2];
  const void* Wv   = d_in[3];
  const void* cq   = d_in[4];
  const void* ck   = d_in[5];
  const void* cv   = d_in[6];
  const void* Wfa  = d_in[7];
  const void* Wfb  = d_in[8];
  const void* dtb  = d_in[9];
  const void* Wb   = d_in[10];
  const void* Alog = d_in[11];
  const void* Wga  = d_in[12];
  const void* Wgb  = d_in[13];
  const void* onw  = d_in[14];
  const void* Wo   = d_in[15];
  char* W = (char*)d_ws;

  const size_t MB = 1024 * 1024;
  const size_t NEED = 114 * MB;
  if (ws_size < NEED) {
    hipMemsetAsync(d_out, 0, (size_t)out_size * 2, stream);
    return;
  }

  float* proj  = (float*)(W);                 // 32M fp32; core aliases
  u16*   swfa  = (u16*)(W);                   // 512K (dead window of proj)
  u16*   swga  = (u16*)(W + 1 * MB);          // 512K
  u16*   swfb  = (u16*)(W + 2 * MB);          // 1M
  u16*   qb    = (u16*)(W + 32 * MB);         // 16M bf16; rmsb aliases
  u16*   kb    = (u16*)(W + 48 * MB);         // 16M bf16; sgb aliases
  u16*   vb    = (u16*)(W + 64 * MB);         // 16M bf16
  u16*   wgb16 = (u16*)(W + 64 * MB);         // 1M (post-scan alias of vb)
  u16*   wo16  = (u16*)(W + 64 * MB);         // 16M (post-SIG alias of vb)
  float* eg    = (float*)(W + 80 * MB);       // 32M fp32
  u16*   x16   = (u16*)(W + 80 * MB);         // 8M (pre-EG alias of eg)
  u16*   w16   = (u16*)(W + 88 * MB);         // 16M (pre-EG alias of eg)
  u16*   flowb = (u16*)(W + 112 * MB);        // 512K
  u16*   glowb = (u16*)(W + 112 * MB + 512 * 1024);
  float* betab = (float*)(W + 113 * MB);      // 256K
  int*   dflag = (int*)(W + 113 * MB + 256 * 1024);
  float* core  = proj;
  u16*   sgb   = kb;
  u16*   rmsb  = qb;

  const dim3 gBig(32, 16);    // C [2048,4096]
  const dim3 gLow(1, 16);     // C [2048,128]
  const dim3 gOut(16, 16);    // C [2048,2048]
  const dim3 gNH(2048, 32);

  detect_dtype<<<1, 256, 0, stream>>>((const u16*)X, dflag);

  // pre-convert (RNE f2bf identical to old in-GEMM conversion -> bit-same)
  cvt_bf16<<<1024, 256, 0, stream>>>(X, x16, 524288, dflag);       // 2048x2048
  cvt_bf16<<<1024, 256, 0, stream>>>(Wq, w16, 1048576, dflag);     // 4096x2048
  gemm_bf16<<<gBig, 256, 0, stream>>>(x16, w16, proj, nullptr, 2048, 4096,
                                      2048, EPI_F32, nullptr, nullptr, dflag);
  conv_silu_norm<<<gNH, 128, 0, stream>>>(proj, cq, qb, 2, dflag);

  cvt_bf16<<<1024, 256, 0, stream>>>(Wk, w16, 1048576, dflag);
  gemm_bf16<<<gBig, 256, 0, stream>>>(x16, w16, proj, nullptr, 2048, 4096,
                                      2048, EPI_F32, nullptr, nullptr, dflag);
  conv_silu_norm<<<gNH, 128, 0, stream>>>(proj, ck, kb, 1, dflag);

  cvt_bf16<<<1024, 256, 0, stream>>>(Wv, w16, 1048576, dflag);
  gemm_bf16<<<gBig, 256, 0, stream>>>(x16, w16, proj, nullptr, 2048, 4096,
                                      2048, EPI_F32, nullptr, nullptr, dflag);
  conv_silu_norm<<<gNH, 128, 0, stream>>>(proj, cv, vb, 0, dflag);

  // low-rank paths (proj now dead until scan -> small weights live there)
  cvt_bf16<<<128, 256, 0, stream>>>(Wfa, swfa, 32768, dflag);      // 128x2048
  gemm_bf16<<<gLow, 256, 0, stream>>>(x16, swfa, nullptr, flowb, 2048, 128,
                                      2048, EPI_BF16, nullptr, nullptr, dflag);
  cvt_bf16<<<128, 256, 0, stream>>>(Wga, swga, 32768, dflag);
  gemm_bf16<<<gLow, 256, 0, stream>>>(x16, swga, nullptr, glowb, 2048, 128,
                                      2048, EPI_BF16, nullptr, nullptr, dflag);
  beta_kernel<<<2048, 64, 0, stream>>>(X, Wb, betab, dflag);

  cvt_bf16<<<256, 256, 0, stream>>>(Wfb, swfb, 65536, dflag);      // 4096x128
  gemm_bf16<<<gBig, 256, 0, stream>>>(flowb, swfb, eg, nullptr, 2048, 4096,
                                      128, EPI_EG, dtb, Alog, dflag);

  scan_kernel<<<256, 256, 0, stream>>>(qb, kb, vb, eg, betab, core);

  cvt_bf16<<<256, 256, 0, stream>>>(Wgb, wgb16, 65536, dflag);     // vb dead
  gemm_bf16<<<gBig, 256, 0, stream>>>(glowb, wgb16, nullptr, sgb, 2048, 4096,
                                      128, EPI_SIG, nullptr, nullptr, dflag);
  rms_gate<<<gNH, 128, 0, stream>>>(core, sgb, onw, rmsb, dflag);

  cvt_bf16<<<1024, 256, 0, stream>>>(Wo, wo16, 1048576, dflag);    // 2048x4096
  gemm_bf16<<<gOut, 256, 0, stream>>>(rmsb, wo16, (float*)d_out, (u16*)d_out,
                                      2048, 2048, 4096, EPI_OUT,
                                      nullptr, nullptr, dflag);
}